// Round 3
// baseline (3747.432 us; speedup 1.0000x reference)
//
#include <hip/hip_runtime.h>

// GLAT: B=64, N=256, D=1024, H=8, DK=64, DI=2048.
// I/O dtype: float32 (per reference). Internal compute: bf16 MFMA + f32 accum.
// adj/slf_attn_mask: int32.

typedef unsigned short u16;
typedef __bf16 bf16_t;
typedef bf16_t bf16x8 __attribute__((ext_vector_type(8)));
typedef float  f32x4  __attribute__((ext_vector_type(4)));
typedef u16    u16x8  __attribute__((ext_vector_type(8)));
typedef u16    u16x4  __attribute__((ext_vector_type(4)));

__device__ __forceinline__ float bf2f(u16 u){
  union { unsigned int i; float f; } c; c.i = ((unsigned int)u) << 16; return c.f;
}
__device__ __forceinline__ u16 f2bf(float f){
  union { float f; unsigned int u; } c; c.f = f;
  unsigned int u = c.u;
  unsigned int r = (u + 0x7fffu + ((u >> 16) & 1u)) >> 16;  // RNE
  return (u16)r;
}

// ---------------- diagnostic fallback: zero d_out (f32) ----------------------
__global__ __launch_bounds__(256) void zero_out(float* out, int n){
  for (int i = blockIdx.x * 256 + threadIdx.x; i < n; i += 256 * 4096) out[i] = 0.f;
}

// -------- weight transpose+convert: src f32 [K][N] -> dst bf16 [(off+n)*K+k] --
__global__ __launch_bounds__(256) void transpose_w(
    const float* __restrict__ src, u16* __restrict__ dst, int K, int N, int dstOff)
{
  __shared__ u16 tile[32][33];
  const int bk = blockIdx.x * 32, bn = blockIdx.y * 32;
  const int t = threadIdx.x;
  const int r = t >> 5, c = t & 31;
  #pragma unroll
  for (int p = 0; p < 4; ++p)
    tile[r + p*8][c] = f2bf(src[(size_t)(bk + r + p*8) * N + bn + c]);
  __syncthreads();
  #pragma unroll
  for (int p = 0; p < 4; ++p)
    dst[(size_t)(dstOff + bn + r + p*8) * K + bk + c] = tile[c][r + p*8];
}

// ---------------- GEMM: C = A[M,K] @ BT[N,K]^T, bf16 MFMA, f32 acc ----------
// A split at k=ksplit between A0/A1 (row stride Astride elements).
// AF32: A is f32 (convert on load). OF32: write f32, else bf16.
// out = maybe_relu(C + bias[col]); bias (f32) may be null.
template<int RELU, int AF32, int OF32>
__global__ __launch_bounds__(256, 2) void gemm_bt(
    const void* __restrict__ A0v, const void* __restrict__ A1v,
    int Astride, int ksplit,
    const u16* __restrict__ BT, int M, int N, int K,
    const float* __restrict__ bias, void* __restrict__ outv, int out_ld)
{
  __shared__ u16 As[128*32];
  __shared__ u16 Bs[128*32];
  const int tid  = threadIdx.x;
  const int lane = tid & 63;
  const int wid  = tid >> 6;
  const int wr = wid >> 1, wc = wid & 1;
  const int m0 = blockIdx.x * 128, n0 = blockIdx.y * 128;

  f32x4 acc[4][4];
  #pragma unroll
  for (int i = 0; i < 4; ++i)
    #pragma unroll
    for (int j = 0; j < 4; ++j)
      acc[i][j] = (f32x4){0.f, 0.f, 0.f, 0.f};

  const int s0 = tid, s1 = tid + 256;          // 16B slots: row=s>>2, off=(s&3)*8
  const int r0 = s0 >> 2, o0 = (s0 & 3) * 8;
  const int r1 = s1 >> 2, o1 = (s1 & 3) * 8;
  const int nk = K >> 5;

  for (int kt = 0; kt < nk; ++kt){
    const int kb = kt * 32;
    const void* Ab = A0v; int kl = kb;
    if (kb >= ksplit){ Ab = A1v; kl = kb - ksplit; }
    u16x8 a0, a1;
    if (AF32){
      const float* Af = (const float*)Ab;
      const size_t i0 = (size_t)(m0 + r0) * Astride + kl + o0;
      const size_t i1 = (size_t)(m0 + r1) * Astride + kl + o1;
      f32x4 p0 = *(const f32x4*)&Af[i0], p1 = *(const f32x4*)&Af[i0 + 4];
      f32x4 p2 = *(const f32x4*)&Af[i1], p3 = *(const f32x4*)&Af[i1 + 4];
      #pragma unroll
      for (int j = 0; j < 4; ++j){
        a0[j] = f2bf(p0[j]); a0[4+j] = f2bf(p1[j]);
        a1[j] = f2bf(p2[j]); a1[4+j] = f2bf(p3[j]);
      }
    } else {
      const u16* Au = (const u16*)Ab;
      a0 = *(const u16x8*)&Au[(size_t)(m0 + r0) * Astride + kl + o0];
      a1 = *(const u16x8*)&Au[(size_t)(m0 + r1) * Astride + kl + o1];
    }
    u16x8 b0 = *(const u16x8*)&BT[(size_t)(n0 + r0) * K + kb + o0];
    u16x8 b1 = *(const u16x8*)&BT[(size_t)(n0 + r1) * K + kb + o1];
    __syncthreads();                 // prev tile fully consumed
    *(u16x8*)&As[s0 * 8] = a0;
    *(u16x8*)&As[s1 * 8] = a1;
    *(u16x8*)&Bs[s0 * 8] = b0;
    *(u16x8*)&Bs[s1 * 8] = b1;
    __syncthreads();

    const int fo = (lane & 15) * 32 + (lane >> 4) * 8;
    bf16x8 af[4], bfv[4];
    #pragma unroll
    for (int i = 0; i < 4; ++i){
      af [i] = *(const bf16x8*)&As[(wr*64 + i*16)*32 + fo];
      bfv[i] = *(const bf16x8*)&Bs[(wc*64 + i*16)*32 + fo];
    }
    #pragma unroll
    for (int i = 0; i < 4; ++i)
      #pragma unroll
      for (int j = 0; j < 4; ++j)
        acc[i][j] = __builtin_amdgcn_mfma_f32_16x16x32_bf16(af[i], bfv[j], acc[i][j], 0, 0, 0);
  }

  // epilogue: C[row][col], row=(lane>>4)*4+r, col=lane&15 (m89-verified)
  const int rb = m0 + wr*64 + (lane >> 4) * 4;
  const int cb = n0 + wc*64 + (lane & 15);
  #pragma unroll
  for (int i = 0; i < 4; ++i){
    #pragma unroll
    for (int j = 0; j < 4; ++j){
      const int col = cb + j*16;
      const float badd = bias ? bias[col] : 0.f;
      #pragma unroll
      for (int r = 0; r < 4; ++r){
        const int row = rb + i*16 + r;
        float y = acc[i][j][r] + badd;
        if (RELU) y = y > 0.f ? y : 0.f;
        if (OF32) ((float*)outv)[(size_t)row * out_ld + col] = y;
        else      ((u16*) outv)[(size_t)row * out_ld + col] = f2bf(y);
      }
    }
  }
}

// ---------------- attention: block = (b_loc,h), thread = q row ---------------
// qkv: quarter-local [4096][1536]; q at h*64, k at 512+h*64, v at 1024+h*64.
__global__ __launch_bounds__(256) void attn_fwd(
    const u16* __restrict__ qkv,
    const int* __restrict__ slf, const int* __restrict__ adj,
    int local, int boff, u16* __restrict__ out)
{
  __shared__ float kf[64*64];
  __shared__ float vf[64*64];
  __shared__ unsigned long long mb[256];

  const int b_loc = blockIdx.x >> 3, h = blockIdx.x & 7;
  const int b = boff + b_loc;          // global batch
  const int t = threadIdx.x;

  // Q row t straight to registers (from quarter-local buffer)
  float qreg[64];
  {
    const size_t gq = ((size_t)(b_loc*256 + t)) * 1536 + h*64;
    #pragma unroll
    for (int g = 0; g < 8; ++g){
      u16x8 w = *(const u16x8*)&qkv[gq + g*8];
      #pragma unroll
      for (int j = 0; j < 8; ++j) qreg[g*8+j] = bf2f(w[j]);
    }
  }

  float m = -1e30f, l = 0.f;
  float oacc[64];
  #pragma unroll
  for (int j = 0; j < 64; ++j) oacc[j] = 0.f;

  const int wid = t >> 6, lane = t & 63;
  for (int c = 0; c < 4; ++c){
    __syncthreads();   // prev chunk fully consumed
    #pragma unroll
    for (int p = 0; p < 2; ++p){
      int s = t + p*256;
      int lr = s >> 3, g = s & 7;
      const size_t rbase = ((size_t)(b_loc*256 + c*64 + lr)) * 1536 + h*64 + g*8;
      u16x8 kw = *(const u16x8*)&qkv[rbase + 512];
      u16x8 vw = *(const u16x8*)&qkv[rbase + 1024];
      #pragma unroll
      for (int j = 0; j < 8; ++j){
        kf[lr*64 + g*8 + j] = bf2f(kw[j]);
        vf[lr*64 + g*8 + j] = bf2f(vw[j]);
      }
    }
    // mask bits: wave handles rows wid, wid+4, ...; lane = key within chunk
    for (int rq = wid; rq < 256; rq += 4){
      const size_t mi = ((size_t)b*256 + rq)*256 + c*64 + lane;
      bool msk = (slf[mi] != 0);
      if (local) msk = msk || (adj[mi] == 0);
      unsigned long long bits = __ballot(msk);
      if (lane == 0) mb[rq] = bits;
    }
    __syncthreads();
    const unsigned long long mbits = mb[t];

    for (int kk = 0; kk < 64; ++kk){
      const float* kr = &kf[kk*64];
      float sdot = 0.f;
      #pragma unroll
      for (int j = 0; j < 64; j += 4){
        f32x4 kv = *(const f32x4*)&kr[j];
        sdot = fmaf(qreg[j+0], kv[0], sdot);
        sdot = fmaf(qreg[j+1], kv[1], sdot);
        sdot = fmaf(qreg[j+2], kv[2], sdot);
        sdot = fmaf(qreg[j+3], kv[3], sdot);
      }
      float sc = sdot * 0.125f;
      if ((mbits >> kk) & 1ULL) sc = -1e9f;
      if (sc > m){
        const float corr = __expf(m - sc);
        l *= corr;
        #pragma unroll
        for (int j = 0; j < 64; ++j) oacc[j] *= corr;
        m = sc;
      }
      const float p = __expf(sc - m);
      l += p;
      const float* vr = &vf[kk*64];
      #pragma unroll
      for (int j = 0; j < 64; j += 4){
        f32x4 vv = *(const f32x4*)&vr[j];
        oacc[j+0] = fmaf(p, vv[0], oacc[j+0]);
        oacc[j+1] = fmaf(p, vv[1], oacc[j+1]);
        oacc[j+2] = fmaf(p, vv[2], oacc[j+2]);
        oacc[j+3] = fmaf(p, vv[3], oacc[j+3]);
      }
    }
  }
  const float inv = 1.f / l;
  const size_t ob = ((size_t)b*256 + t)*512 + h*64;   // global [B,N,H*DK]
  #pragma unroll
  for (int g = 0; g < 8; ++g){
    u16x8 ov;
    #pragma unroll
    for (int j = 0; j < 8; ++j) ov[j] = f2bf(oacc[g*8+j] * inv);
    *(u16x8*)&out[ob + g*8] = ov;
  }
}

// -------- fused residual + LayerNorm + npm; a bf16, res f32|bf16, out bf16 ---
// In-place (out == a) is safe: each thread reads its 4 elems before writing.
template<int RF32>
__global__ __launch_bounds__(256) void ln_fused(
    const u16* a, const void* __restrict__ res,
    const float* __restrict__ sc, const float* __restrict__ bs,
    const float* __restrict__ npm, u16* out)
{
  const int row = blockIdx.x, t = threadIdx.x;
  const size_t bse = (size_t)row * 1024 + t*4;
  u16x4 av = *(const u16x4*)&a[bse];
  float rv[4];
  if (RF32){
    f32x4 q = *(const f32x4*)&((const float*)res)[bse];
    #pragma unroll
    for (int j = 0; j < 4; ++j) rv[j] = q[j];
  } else {
    u16x4 q = *(const u16x4*)&((const u16*)res)[bse];
    #pragma unroll
    for (int j = 0; j < 4; ++j) rv[j] = bf2f(q[j]);
  }
  float vv[4]; float s = 0.f, sq = 0.f;
  #pragma unroll
  for (int j = 0; j < 4; ++j){
    vv[j] = bf2f(av[j]) + rv[j];
    s += vv[j]; sq += vv[j]*vv[j];
  }
  #pragma unroll
  for (int i = 1; i < 64; i <<= 1){
    s  += __shfl_xor(s,  i, 64);
    sq += __shfl_xor(sq, i, 64);
  }
  __shared__ float red[8];
  const int wid = t >> 6, lane = t & 63;
  if (lane == 0){ red[wid] = s; red[4 + wid] = sq; }
  __syncthreads();
  s  = red[0] + red[1] + red[2] + red[3];
  sq = red[4] + red[5] + red[6] + red[7];
  const float mean = s * (1.f/1024.f);
  const float var  = sq * (1.f/1024.f) - mean*mean;
  const float rstd = rsqrtf(var + 1e-5f);
  const float nm   = npm[row];
  u16x4 ov;
  #pragma unroll
  for (int j = 0; j < 4; ++j){
    float y = (vv[j] - mean) * rstd * sc[t*4+j] + bs[t*4+j];
    ov[j] = f2bf(y * nm);
  }
  *(u16x4*)&out[bse] = ov;
}

// ---------------- launcher ---------------------------------------------------
extern "C" void kernel_launch(void* const* d_in, const int* in_sizes, int n_in,
                              void* d_out, int out_size, void* d_ws, size_t ws_size,
                              hipStream_t stream)
{
  // ws layout (u16 elements), total 58,720,256 el = 112 MiB (proven available):
  //  W  [0,        8,388,608): wqkvT|woT|w1T|w2T|fcT
  //  A  [8,388,608,25,165,824): qkvq[4096][1536] @ +0 (6.29M)
  //                             attnb[16384][512] @ +6,291,456 (8.39M)
  //                             ln1[16384][1024] overwrites A after out-proj
  //  B  [25,165,824,41,943,040): xg
  //  C  [41,943,040,58,720,256): tmp; xl = in-place LN over tmp (layer 1)
  //  hbuf[8192][2048] bf16 lives in d_out (dead before final f32 GEMM).
  const size_t NEED = 58720256ull * 2ull;
  if (ws_size < NEED){                       // diagnostic: signal instead of crash
    zero_out<<<4096, 256, 0, stream>>>((float*)d_out, out_size);
    return;
  }

  const float* x   = (const float*)d_in[0];
  const int*   adj = (const int*)d_in[1];
  const float* npm = (const float*)d_in[2];
  const int*   slf = (const int*)d_in[3];
  const float* fcw = (const float*)d_in[30];
  const float* fcb = (const float*)d_in[31];

  u16* ws    = (u16*)d_ws;
  u16* wqkvT = ws;                     // 1536 rows x 1024
  u16* woT   = ws + 1572864;           // 1024 rows x 512
  u16* w1T   = ws + 2097152;           // 2048 rows x 1024
  u16* w2T   = ws + 4194304;           // 1024 rows x 2048
  u16* fcT   = ws + 6291456;           // 1024 rows x 2048
  u16* qkvq  = ws + 8388608;           // 4096*1536 (batch quarter)
  u16* attnb = ws + 14680064;          // 16384*512
  u16* ln1   = ws + 8388608;           // 16384*1024 (overwrites A)
  u16* xg    = ws + 25165824;          // 16384*1024
  u16* tmp   = ws + 41943040;          // 16384*1024 (also xl, in-place)
  u16* hbuf  = (u16*)d_out;            // 8192*2048 scratch inside d_out

  transpose_w<<<dim3(64, 32), 256, 0, stream>>>(fcw, fcT, 2048, 1024, 0);

  for (int L = 0; L < 2; ++L){
    const int bi = 4 + L*13;
    const float* wq  = (const float*)d_in[bi+0];
    const float* wk  = (const float*)d_in[bi+1];
    const float* wv  = (const float*)d_in[bi+2];
    const float* wo  = (const float*)d_in[bi+3];
    const float* bo  = (const float*)d_in[bi+4];
    const float* l1s = (const float*)d_in[bi+5];
    const float* l1b = (const float*)d_in[bi+6];
    const float* w1  = (const float*)d_in[bi+7];
    const float* b1  = (const float*)d_in[bi+8];
    const float* w2  = (const float*)d_in[bi+9];
    const float* b2  = (const float*)d_in[bi+10];
    const float* l2s = (const float*)d_in[bi+11];
    const float* l2b = (const float*)d_in[bi+12];

    transpose_w<<<dim3(32, 16), 256, 0, stream>>>(wq, wqkvT, 1024, 512, 0);
    transpose_w<<<dim3(32, 16), 256, 0, stream>>>(wk, wqkvT, 1024, 512, 512);
    transpose_w<<<dim3(32, 16), 256, 0, stream>>>(wv, wqkvT, 1024, 512, 1024);
    transpose_w<<<dim3(16, 32), 256, 0, stream>>>(wo, woT, 512, 1024, 0);
    transpose_w<<<dim3(32, 64), 256, 0, stream>>>(w1, w1T, 1024, 2048, 0);
    transpose_w<<<dim3(64, 32), 256, 0, stream>>>(w2, w2T, 2048, 1024, 0);

    // QKV + attention in batch quarters (qkvq reused)
    for (int q = 0; q < 4; ++q){
      const float* xq = x + (size_t)q*4096*1024;
      gemm_bt<0,1,0><<<dim3(32, 12), 256, 0, stream>>>(
          xq, xq, 1024, 1024, wqkvT, 4096, 1536, 1024, nullptr, qkvq, 1536);
      attn_fwd<<<128, 256, 0, stream>>>(qkvq, slf, adj, L, q*16, attnb);
    }
    // out-proj + bo -> tmp
    gemm_bt<0,0,0><<<dim3(128, 8), 256, 0, stream>>>(
        attnb, attnb, 512, 512, woT, 16384, 1024, 512, bo, tmp, 1024);
    // ln1 = LN(tmp + x) * npm  (overwrites A region)
    ln_fused<1><<<16384, 256, 0, stream>>>(tmp, x, l1s, l1b, npm, ln1);
    // FFN in 2 row-chunks of 8192 (hbuf in d_out)
    for (int c = 0; c < 2; ++c){
      const u16* a1 = ln1 + (size_t)c*8192*1024;
      gemm_bt<1,0,0><<<dim3(64, 16), 256, 0, stream>>>(
          a1, a1, 1024, 1024, w1T, 8192, 2048, 1024, b1, hbuf, 2048);
      gemm_bt<0,0,0><<<dim3(64, 8), 256, 0, stream>>>(
          hbuf, hbuf, 2048, 2048, w2T, 8192, 1024, 2048, b2,
          tmp + (size_t)c*8192*1024, 1024);
    }
    // xout = LN(tmp + ln1) * npm; layer 0 -> xg, layer 1 -> in-place (xl = tmp)
    ln_fused<0><<<16384, 256, 0, stream>>>(tmp, ln1, l2s, l2b, npm, L ? tmp : xg);
  }

  // final: [xg | xl] @ fcT + fc_b -> d_out (f32), K split at 1024
  gemm_bt<0,0,1><<<dim3(128, 8), 256, 0, stream>>>(
      xg, tmp, 1024, 1024, fcT, 16384, 1024, 2048, fcb, d_out, 1024);
}

// Round 4
// 903.360 us; speedup vs baseline: 4.1483x; 4.1483x over previous
//
#include <hip/hip_runtime.h>

// GLAT: B=64, N=256, D=1024, H=8, DK=64, DI=2048.
// I/O dtype: float32. Internal: bf16 MFMA + f32 accum. adj/slf: int32.

typedef unsigned short u16;
typedef unsigned long long u64;
typedef __bf16 bf16_t;
typedef bf16_t bf16x8 __attribute__((ext_vector_type(8)));
typedef float  f32x4  __attribute__((ext_vector_type(4)));
typedef u16    u16x8  __attribute__((ext_vector_type(8)));
typedef u16    u16x4  __attribute__((ext_vector_type(4)));

__device__ __forceinline__ float bf2f(u16 u){
  union { unsigned int i; float f; } c; c.i = ((unsigned int)u) << 16; return c.f;
}
__device__ __forceinline__ u16 f2bf(float f){
  union { float f; unsigned int u; } c; c.f = f;
  unsigned int u = c.u;
  unsigned int r = (u + 0x7fffu + ((u >> 16) & 1u)) >> 16;  // RNE
  return (u16)r;
}

// ---------------- diagnostic fallback: zero d_out (f32) ----------------------
__global__ __launch_bounds__(256) void zero_out(float* out, int n){
  for (int i = blockIdx.x * 256 + threadIdx.x; i < n; i += 256 * 4096) out[i] = 0.f;
}

// -------- weight transpose+convert: src f32 [K][N] -> dst bf16 [(off+n)*K+k] --
__global__ __launch_bounds__(256) void transpose_w(
    const float* __restrict__ src, u16* __restrict__ dst, int K, int N, int dstOff)
{
  __shared__ u16 tile[32][33];
  const int bk = blockIdx.x * 32, bn = blockIdx.y * 32;
  const int t = threadIdx.x;
  const int r = t >> 5, c = t & 31;
  #pragma unroll
  for (int p = 0; p < 4; ++p)
    tile[r + p*8][c] = f2bf(src[(size_t)(bk + r + p*8) * N + bn + c]);
  __syncthreads();
  #pragma unroll
  for (int p = 0; p < 4; ++p)
    dst[(size_t)(dstOff + bn + r + p*8) * K + bk + c] = tile[c][r + p*8];
}

// ---------------- GEMM: C = A[M,K] @ BT[N,K]^T, bf16 MFMA, f32 acc ----------
template<int RELU, int AF32, int OF32>
__global__ __launch_bounds__(256, 2) void gemm_bt(
    const void* __restrict__ A0v, const void* __restrict__ A1v,
    int Astride, int ksplit,
    const u16* __restrict__ BT, int M, int N, int K,
    const float* __restrict__ bias, void* __restrict__ outv, int out_ld)
{
  __shared__ u16 As[128*32];
  __shared__ u16 Bs[128*32];
  const int tid  = threadIdx.x;
  const int lane = tid & 63;
  const int wid  = tid >> 6;
  const int wr = wid >> 1, wc = wid & 1;
  const int m0 = blockIdx.x * 128, n0 = blockIdx.y * 128;

  f32x4 acc[4][4];
  #pragma unroll
  for (int i = 0; i < 4; ++i)
    #pragma unroll
    for (int j = 0; j < 4; ++j)
      acc[i][j] = (f32x4){0.f, 0.f, 0.f, 0.f};

  const int s0 = tid, s1 = tid + 256;
  const int r0 = s0 >> 2, o0 = (s0 & 3) * 8;
  const int r1 = s1 >> 2, o1 = (s1 & 3) * 8;
  const int nk = K >> 5;

  for (int kt = 0; kt < nk; ++kt){
    const int kb = kt * 32;
    const void* Ab = A0v; int kl = kb;
    if (kb >= ksplit){ Ab = A1v; kl = kb - ksplit; }
    u16x8 a0, a1;
    if (AF32){
      const float* Af = (const float*)Ab;
      const size_t i0 = (size_t)(m0 + r0) * Astride + kl + o0;
      const size_t i1 = (size_t)(m0 + r1) * Astride + kl + o1;
      f32x4 p0 = *(const f32x4*)&Af[i0], p1 = *(const f32x4*)&Af[i0 + 4];
      f32x4 p2 = *(const f32x4*)&Af[i1], p3 = *(const f32x4*)&Af[i1 + 4];
      #pragma unroll
      for (int j = 0; j < 4; ++j){
        a0[j] = f2bf(p0[j]); a0[4+j] = f2bf(p1[j]);
        a1[j] = f2bf(p2[j]); a1[4+j] = f2bf(p3[j]);
      }
    } else {
      const u16* Au = (const u16*)Ab;
      a0 = *(const u16x8*)&Au[(size_t)(m0 + r0) * Astride + kl + o0];
      a1 = *(const u16x8*)&Au[(size_t)(m0 + r1) * Astride + kl + o1];
    }
    u16x8 b0 = *(const u16x8*)&BT[(size_t)(n0 + r0) * K + kb + o0];
    u16x8 b1 = *(const u16x8*)&BT[(size_t)(n0 + r1) * K + kb + o1];
    __syncthreads();
    *(u16x8*)&As[s0 * 8] = a0;
    *(u16x8*)&As[s1 * 8] = a1;
    *(u16x8*)&Bs[s0 * 8] = b0;
    *(u16x8*)&Bs[s1 * 8] = b1;
    __syncthreads();

    const int fo = (lane & 15) * 32 + (lane >> 4) * 8;
    bf16x8 af[4], bfv[4];
    #pragma unroll
    for (int i = 0; i < 4; ++i){
      af [i] = *(const bf16x8*)&As[(wr*64 + i*16)*32 + fo];
      bfv[i] = *(const bf16x8*)&Bs[(wc*64 + i*16)*32 + fo];
    }
    #pragma unroll
    for (int i = 0; i < 4; ++i)
      #pragma unroll
      for (int j = 0; j < 4; ++j)
        acc[i][j] = __builtin_amdgcn_mfma_f32_16x16x32_bf16(af[i], bfv[j], acc[i][j], 0, 0, 0);
  }

  const int rb = m0 + wr*64 + (lane >> 4) * 4;
  const int cb = n0 + wc*64 + (lane & 15);
  #pragma unroll
  for (int i = 0; i < 4; ++i){
    #pragma unroll
    for (int j = 0; j < 4; ++j){
      const int col = cb + j*16;
      const float badd = bias ? bias[col] : 0.f;
      #pragma unroll
      for (int r = 0; r < 4; ++r){
        const int row = rb + i*16 + r;
        float y = acc[i][j][r] + badd;
        if (RELU) y = y > 0.f ? y : 0.f;
        if (OF32) ((float*)outv)[(size_t)row * out_ld + col] = y;
        else      ((u16*) outv)[(size_t)row * out_ld + col] = f2bf(y);
      }
    }
  }
}

// -------- mask pack: bit k of mb[row][c] = mask(row, c*64+k) -----------------
__global__ __launch_bounds__(256) void mask_pack(
    const int* __restrict__ slf, const int* __restrict__ adj,
    u64* __restrict__ mb_g, u64* __restrict__ mb_l)
{
  const int idx  = blockIdx.x * 4 + (threadIdx.x >> 6);  // (row, c) pair
  const int lane = threadIdx.x & 63;
  const size_t mi = (size_t)(idx >> 2) * 256 + (size_t)(idx & 3) * 64 + lane;
  const bool g = slf[mi] != 0;
  const bool l = g || (adj[mi] == 0);
  const u64 bg = __ballot(g);
  const u64 bl = __ballot(l);
  if (lane == 0){ mb_g[idx] = bg; mb_l[idx] = bl; }
}

// ---------------- MFMA flash attention ---------------------------------------
// block = (b_loc, h, qtile of 128 rows); 4 waves x 32 q-rows.
// qkv: half-local [8192][1536]; q @ h*64, k @ 512+h*64, v @ 1024+h*64.
__global__ __launch_bounds__(256) void attn_mfma(
    const u16* __restrict__ qkv, const u64* __restrict__ mb,
    int boff, u16* __restrict__ out)
{
  __shared__ u16 kbuf[64*64];     // [key][dim], swizzled col ^= (key&7)<<3
  __shared__ u16 vtbuf[64*64];    // [dim][key], swizzled col ^= (dim&7)<<3
  __shared__ u16 pbuf[4][32*64];  // per-wave P [row][key], swizzled

  const int b_loc = blockIdx.x >> 4;
  const int h     = (blockIdx.x >> 1) & 7;
  const int qt    = blockIdx.x & 1;
  const int b     = boff + b_loc;
  const int t     = threadIdx.x;
  const int w     = t >> 6, lane = t & 63;
  const int l15   = lane & 15, l4 = lane >> 4;

  // Q fragments (A-frag): rows qt*128 + w*32 + i*16 + l15, dims kc*32 + l4*8
  bf16x8 qf[2][2];
  {
    const int rbase = b_loc*256 + qt*128 + w*32;
    #pragma unroll
    for (int i = 0; i < 2; ++i)
      #pragma unroll
      for (int kc = 0; kc < 2; ++kc)
        qf[i][kc] = *(const bf16x8*)&qkv[(size_t)(rbase + i*16 + l15)*1536 + h*64 + kc*32 + l4*8];
  }

  f32x4 acc_o[2][4];
  float m_[2][4], l_[2][4];
  #pragma unroll
  for (int i = 0; i < 2; ++i){
    #pragma unroll
    for (int j = 0; j < 4; ++j) acc_o[i][j] = (f32x4){0.f,0.f,0.f,0.f};
    #pragma unroll
    for (int r = 0; r < 4; ++r){ m_[i][r] = -1e30f; l_[i][r] = 0.f; }
  }

  for (int c = 0; c < 4; ++c){
    __syncthreads();                       // prior chunk fully consumed
    {   // stage K and V^T (swizzled); thread -> key row t>>2, dim group (t&3)*16
      const int kr = t >> 2, dg = (t & 3) * 16;
      const size_t rbase = (size_t)(b_loc*256 + c*64 + kr)*1536 + h*64 + dg;
      u16x8 k0 = *(const u16x8*)&qkv[rbase + 512];
      u16x8 k1 = *(const u16x8*)&qkv[rbase + 512 + 8];
      u16x8 v0 = *(const u16x8*)&qkv[rbase + 1024];
      u16x8 v1 = *(const u16x8*)&qkv[rbase + 1024 + 8];
      const int sw = (kr & 7) << 3;
      *(u16x8*)&kbuf[kr*64 + (dg ^ sw)]       = k0;
      *(u16x8*)&kbuf[kr*64 + ((dg + 8) ^ sw)] = k1;
      #pragma unroll
      for (int e = 0; e < 8; ++e){
        const int d0 = dg + e, d1 = dg + 8 + e;
        vtbuf[d0*64 + (kr ^ ((d0 & 7) << 3))] = v0[e];
        vtbuf[d1*64 + (kr ^ ((d1 & 7) << 3))] = v1[e];
      }
    }
    __syncthreads();

    // K fragments (B-frag): key jb*16 + l15, dims kc*32 + l4*8
    bf16x8 kfr[4][2];
    #pragma unroll
    for (int jb = 0; jb < 4; ++jb){
      const int key = jb*16 + l15;
      const int sw = (key & 7) << 3;
      #pragma unroll
      for (int kc = 0; kc < 2; ++kc)
        kfr[jb][kc] = *(const bf16x8*)&kbuf[key*64 + ((kc*32 + l4*8) ^ sw)];
    }
    // S = Q K^T : C-layout row=q (i*16 + l4*4 + r), col=key (jb*16 + l15)
    f32x4 s_[2][4];
    #pragma unroll
    for (int i = 0; i < 2; ++i)
      #pragma unroll
      for (int jb = 0; jb < 4; ++jb){
        f32x4 a = (f32x4){0.f,0.f,0.f,0.f};
        a = __builtin_amdgcn_mfma_f32_16x16x32_bf16(qf[i][0], kfr[jb][0], a, 0,0,0);
        a = __builtin_amdgcn_mfma_f32_16x16x32_bf16(qf[i][1], kfr[jb][1], a, 0,0,0);
        s_[i][jb] = a;
      }

    // mask + online softmax (16-lane row reduce) + P -> pbuf (bf16, swizzled)
    #pragma unroll
    for (int i = 0; i < 2; ++i){
      #pragma unroll
      for (int r = 0; r < 4; ++r){
        const int prow = i*16 + l4*4 + r;           // 0..31 within wave tile
        const int qrow = qt*128 + w*32 + prow;
        const u64 bits = mb[((size_t)b*256 + qrow)*4 + c];
        float sv[4];
        #pragma unroll
        for (int jb = 0; jb < 4; ++jb){
          float xv = s_[i][jb][r] * 0.125f;
          if ((bits >> (jb*16 + l15)) & 1ull) xv = -1e9f;
          sv[jb] = xv;
        }
        float mx = fmaxf(fmaxf(sv[0], sv[1]), fmaxf(sv[2], sv[3]));
        #pragma unroll
        for (int d = 1; d < 16; d <<= 1)
          mx = fmaxf(mx, __shfl_xor(mx, d, 64));
        const float mnew = fmaxf(m_[i][r], mx);
        const float corr = __expf(m_[i][r] - mnew);
        m_[i][r] = mnew;
        float ps = 0.f;
        const int swp = (prow & 7) << 3;
        #pragma unroll
        for (int jb = 0; jb < 4; ++jb){
          const float p = __expf(sv[jb] - mnew);
          ps += p;
          pbuf[w][prow*64 + ((jb*16 + l15) ^ swp)] = f2bf(p);
        }
        #pragma unroll
        for (int d = 1; d < 16; d <<= 1)
          ps += __shfl_xor(ps, d, 64);
        l_[i][r] = l_[i][r] * corr + ps;
        #pragma unroll
        for (int j2 = 0; j2 < 4; ++j2) acc_o[i][j2][r] *= corr;
      }
    }

    // V fragments (B-frag over dims) + PV accumulate
    bf16x8 vfr[4][2];
    #pragma unroll
    for (int j2 = 0; j2 < 4; ++j2){
      const int dim = j2*16 + l15;
      const int sw = (dim & 7) << 3;
      #pragma unroll
      for (int kc = 0; kc < 2; ++kc)
        vfr[j2][kc] = *(const bf16x8*)&vtbuf[dim*64 + ((kc*32 + l4*8) ^ sw)];
    }
    #pragma unroll
    for (int i = 0; i < 2; ++i){
      const int prow = i*16 + l15;
      const int swp = (prow & 7) << 3;
      bf16x8 pa0 = *(const bf16x8*)&pbuf[w][prow*64 + ((l4*8) ^ swp)];
      bf16x8 pa1 = *(const bf16x8*)&pbuf[w][prow*64 + ((32 + l4*8) ^ swp)];
      #pragma unroll
      for (int j2 = 0; j2 < 4; ++j2){
        acc_o[i][j2] = __builtin_amdgcn_mfma_f32_16x16x32_bf16(pa0, vfr[j2][0], acc_o[i][j2], 0,0,0);
        acc_o[i][j2] = __builtin_amdgcn_mfma_f32_16x16x32_bf16(pa1, vfr[j2][1], acc_o[i][j2], 0,0,0);
      }
    }
  }

  // epilogue: out[b*256+qrow][h*64 + dim]
  #pragma unroll
  for (int i = 0; i < 2; ++i){
    #pragma unroll
    for (int r = 0; r < 4; ++r){
      const int qrow = qt*128 + w*32 + i*16 + l4*4 + r;
      const float inv = 1.f / l_[i][r];
      const size_t ob = ((size_t)b*256 + qrow)*512 + h*64;
      #pragma unroll
      for (int j2 = 0; j2 < 4; ++j2)
        out[ob + j2*16 + l15] = f2bf(acc_o[i][j2][r] * inv);
    }
  }
}

// -------- fused residual + LayerNorm + npm; a bf16, res f32|bf16, out bf16 ---
template<int RF32>
__global__ __launch_bounds__(256) void ln_fused(
    const u16* a, const void* __restrict__ res,
    const float* __restrict__ sc, const float* __restrict__ bs,
    const float* __restrict__ npm, u16* out)
{
  const int row = blockIdx.x, t = threadIdx.x;
  const size_t bse = (size_t)row * 1024 + t*4;
  u16x4 av = *(const u16x4*)&a[bse];
  float rv[4];
  if (RF32){
    f32x4 q = *(const f32x4*)&((const float*)res)[bse];
    #pragma unroll
    for (int j = 0; j < 4; ++j) rv[j] = q[j];
  } else {
    u16x4 q = *(const u16x4*)&((const u16*)res)[bse];
    #pragma unroll
    for (int j = 0; j < 4; ++j) rv[j] = bf2f(q[j]);
  }
  float vv[4]; float s = 0.f, sq = 0.f;
  #pragma unroll
  for (int j = 0; j < 4; ++j){
    vv[j] = bf2f(av[j]) + rv[j];
    s += vv[j]; sq += vv[j]*vv[j];
  }
  #pragma unroll
  for (int i = 1; i < 64; i <<= 1){
    s  += __shfl_xor(s,  i, 64);
    sq += __shfl_xor(sq, i, 64);
  }
  __shared__ float red[8];
  const int wid = t >> 6, lane = t & 63;
  if (lane == 0){ red[wid] = s; red[4 + wid] = sq; }
  __syncthreads();
  s  = red[0] + red[1] + red[2] + red[3];
  sq = red[4] + red[5] + red[6] + red[7];
  const float mean = s * (1.f/1024.f);
  const float var  = sq * (1.f/1024.f) - mean*mean;
  const float rstd = rsqrtf(var + 1e-5f);
  const float nm   = npm[row];
  u16x4 ov;
  #pragma unroll
  for (int j = 0; j < 4; ++j){
    float y = (vv[j] - mean) * rstd * sc[t*4+j] + bs[t*4+j];
    ov[j] = f2bf(y * nm);
  }
  *(u16x4*)&out[bse] = ov;
}

// ---------------- launcher ---------------------------------------------------
extern "C" void kernel_launch(void* const* d_in, const int* in_sizes, int n_in,
                              void* d_out, int out_size, void* d_ws, size_t ws_size,
                              hipStream_t stream)
{
  // ws (u16 el), 112 MiB total (proven):
  //  W   [0, 8388608): wqkvT|woT|w1T|w2T|fcT
  //  ln1 [8388608, 25165824)   (qkvh [8192][1536] aliases its head per half)
  //  tmp [25165824, 41943040)  (also xl in-place at layer-1 end)
  //  xg  [41943040, 58720256)
  // d_out (u16 view): attnb [0,8388608) | hbuf [8388608,25165824)
  //                   mb_g @ byte 50331648 | mb_l @ byte 50855936
  const size_t NEED = 58720256ull * 2ull;
  if (ws_size < NEED){
    zero_out<<<4096, 256, 0, stream>>>((float*)d_out, out_size);
    return;
  }

  const float* x   = (const float*)d_in[0];
  const int*   adj = (const int*)d_in[1];
  const float* npm = (const float*)d_in[2];
  const int*   slf = (const int*)d_in[3];
  const float* fcw = (const float*)d_in[30];
  const float* fcb = (const float*)d_in[31];

  u16* ws    = (u16*)d_ws;
  u16* wqkvT = ws;
  u16* woT   = ws + 1572864;
  u16* w1T   = ws + 2097152;
  u16* w2T   = ws + 4194304;
  u16* fcT   = ws + 6291456;
  u16* qkvh  = ws + 8388608;           // [8192][1536] per half
  u16* ln1   = ws + 8388608;           // [16384][1024]
  u16* tmp   = ws + 25165824;          // [16384][1024]
  u16* xg    = ws + 41943040;          // [16384][1024]

  u16* dout16 = (u16*)d_out;
  u16* attnb  = dout16;                          // [16384][512] bf16
  u16* hbuf   = dout16 + 8388608;                // [8192][2048] bf16 (FFN chunk)
  u64* mb_g   = (u64*)((char*)d_out + 50331648);
  u64* mb_l   = (u64*)((char*)d_out + 50855936);

  transpose_w<<<dim3(64, 32), 256, 0, stream>>>(fcw, fcT, 2048, 1024, 0);
  mask_pack<<<16384, 256, 0, stream>>>(slf, adj, mb_g, mb_l);

  for (int L = 0; L < 2; ++L){
    const int bi = 4 + L*13;
    const float* wq  = (const float*)d_in[bi+0];
    const float* wk  = (const float*)d_in[bi+1];
    const float* wv  = (const float*)d_in[bi+2];
    const float* wo  = (const float*)d_in[bi+3];
    const float* bo  = (const float*)d_in[bi+4];
    const float* l1s = (const float*)d_in[bi+5];
    const float* l1b = (const float*)d_in[bi+6];
    const float* w1  = (const float*)d_in[bi+7];
    const float* b1  = (const float*)d_in[bi+8];
    const float* w2  = (const float*)d_in[bi+9];
    const float* b2  = (const float*)d_in[bi+10];
    const float* l2s = (const float*)d_in[bi+11];
    const float* l2b = (const float*)d_in[bi+12];

    transpose_w<<<dim3(32, 16), 256, 0, stream>>>(wq, wqkvT, 1024, 512, 0);
    transpose_w<<<dim3(32, 16), 256, 0, stream>>>(wk, wqkvT, 1024, 512, 512);
    transpose_w<<<dim3(32, 16), 256, 0, stream>>>(wv, wqkvT, 1024, 512, 1024);
    transpose_w<<<dim3(16, 32), 256, 0, stream>>>(wo, woT, 512, 1024, 0);
    transpose_w<<<dim3(32, 64), 256, 0, stream>>>(w1, w1T, 1024, 2048, 0);
    transpose_w<<<dim3(64, 32), 256, 0, stream>>>(w2, w2T, 2048, 1024, 0);

    // QKV + attention in batch halves
    for (int hf = 0; hf < 2; ++hf){
      const float* xh = x + (size_t)hf*8192*1024;
      gemm_bt<0,1,0><<<dim3(64, 12), 256, 0, stream>>>(
          xh, xh, 1024, 1024, wqkvT, 8192, 1536, 1024, nullptr, qkvh, 1536);
      attn_mfma<<<512, 256, 0, stream>>>(qkvh, L ? mb_l : mb_g, hf*32, attnb);
    }
    // out-proj + bo -> tmp
    gemm_bt<0,0,0><<<dim3(128, 8), 256, 0, stream>>>(
        attnb, attnb, 512, 512, woT, 16384, 1024, 512, bo, tmp, 1024);
    // ln1 = LN(tmp + x) * npm
    ln_fused<1><<<16384, 256, 0, stream>>>(tmp, x, l1s, l1b, npm, ln1);
    // FFN in 2 row-chunks of 8192 (hbuf in d_out)
    for (int c = 0; c < 2; ++c){
      const u16* a1 = ln1 + (size_t)c*8192*1024;
      gemm_bt<1,0,0><<<dim3(64, 16), 256, 0, stream>>>(
          a1, a1, 1024, 1024, w1T, 8192, 2048, 1024, b1, hbuf, 2048);
      gemm_bt<0,0,0><<<dim3(64, 8), 256, 0, stream>>>(
          hbuf, hbuf, 2048, 2048, w2T, 8192, 1024, 2048, b2,
          tmp + (size_t)c*8192*1024, 1024);
    }
    // xout = LN(tmp + ln1) * npm; layer0 -> xg, layer1 -> in-place (xl = tmp)
    ln_fused<0><<<16384, 256, 0, stream>>>(tmp, ln1, l2s, l2b, npm, L ? tmp : xg);
  }

  // final: [xg | xl] @ fcT + fc_b -> d_out (f32), K split at 1024
  gemm_bt<0,0,1><<<dim3(128, 8), 256, 0, stream>>>(
      xg, tmp, 1024, 1024, fcT, 16384, 1024, 2048, fcb, d_out, 1024);
}